// Round 4
// baseline (531.354 us; speedup 1.0000x reference)
//
#include <hip/hip_runtime.h>
#include <math.h>

// Problem constants
#define BB 2
#define RR 4096
#define NRAY (BB*RR)            // 8192
#define SC 48
#define NSAMP (NRAY*SC)         // 393216
#define CF 32
#define HID 64
#define ODIM 33                 // 1 sigma + 32 rgb
#define PRES 256
#define PLANE_HW (PRES*PRES)    // 65536
#define RAY_START 0.1f
#define RAY_END 2.0f
#define DELTA ((RAY_END-RAY_START)/(SC-1))

// workspace layout (in floats)
#define OFF_PLANES2  ((size_t)0)                        // 6*65536*64 bf16 = 12582912 floats
#define OFF_DEPTH_C  ((size_t)12582912)                 // 393216
#define OFF_SIGMA_C  (OFF_DEPTH_C + 393216)             // 393216
#define OFF_RGB_C    (OFF_SIGMA_C + 393216)             // 12582912
#define OFF_DEPTH_F  (OFF_RGB_C + 12582912)             // 393216
#define OFF_SIGMA_F  (OFF_DEPTH_F + 393216)             // 393216
#define OFF_RGB_F    (OFF_SIGMA_F + 393216)             // 12582912
#define OFF_MINMAX   (OFF_RGB_F + 12582912)             // 2 uints (+2 pad)
#define OFF_W2T      (OFF_MINMAX + 4)                   // 33*64 = 2112 floats (w2 transposed)

__device__ __forceinline__ float softplusf(float x) {
    return fmaxf(x, 0.f) + log1pf(expf(-fabsf(x)));
}
__device__ __forceinline__ unsigned short f2bf(float f) {
    union { float f; unsigned int u; } v; v.f = f;
    unsigned int r = v.u + 0x7fffu + ((v.u >> 16) & 1u);   // RNE
    return (unsigned short)(r >> 16);
}
__device__ __forceinline__ unsigned int pack2(float lo, float hi) {
    return (unsigned int)f2bf(lo) | ((unsigned int)f2bf(hi) << 16);
}
// dword holding 2 bf16 channels -> fma both into fp32 accumulators
__device__ __forceinline__ void fma2(unsigned int u, float w, float& a0, float& a1) {
    union { unsigned int i; float f; } lo, hi;
    lo.i = u << 16;
    hi.i = u & 0xffff0000u;
    a0 = fmaf(w, lo.f, a0);
    a1 = fmaf(w, hi.f, a1);
}

// ---------------------------------------------------------------------------
// Kernel 1: precompute planes2[bp][y][x][j] = bf16( sum_c planes[bp][c][y][x] * w1[c][j] )
// (bilinear+mean are linear, softplus comes after -> fold w1 into the texels once).
// Also: w2t[k][j] = w2[j][k], minmax init.
// grid: 6*256 rows, 256 threads = one texel per thread (x), coalesced loads per c.
__global__ __launch_bounds__(256) void precompute(
    const float* __restrict__ planes, const float* __restrict__ w1,
    const float* __restrict__ w2,
    unsigned short* __restrict__ planes2, float* __restrict__ w2t,
    unsigned int* __restrict__ minmax)
{
    if (blockIdx.x == 0) {
        if (threadIdx.x == 0) {
            minmax[0] = 0xFFFFFFFFu;   // atomicMin target (positive-float uint order)
            minmax[1] = 0u;            // atomicMax target
        }
        if (threadIdx.x < ODIM) {
            int k = threadIdx.x;
            for (int j = 0; j < HID; ++j) w2t[k * HID + j] = w2[j * ODIM + k];
        }
    }
    int row = blockIdx.x;
    int bp = row >> 8, y = row & 255;
    int x = threadIdx.x;
    const float* src = planes + (size_t)bp * CF * PLANE_HW + (size_t)y * PRES + x;
    float acc[HID];
    #pragma unroll
    for (int j = 0; j < HID; ++j) acc[j] = 0.f;
    for (int c = 0; c < CF; ++c) {
        float f = src[(size_t)c * PLANE_HW];
        #pragma unroll
        for (int j = 0; j < HID; ++j) acc[j] = fmaf(f, w1[c * HID + j], acc[j]);
    }
    unsigned short* dst = planes2 + ((size_t)bp * PLANE_HW + (size_t)y * PRES + x) * HID;
    #pragma unroll
    for (int q = 0; q < 4; ++q) {
        uint4 u;
        u.x = pack2(acc[q*8+0], acc[q*8+1]);
        u.y = pack2(acc[q*8+2], acc[q*8+3]);
        u.z = pack2(acc[q*8+4], acc[q*8+5]);
        u.w = pack2(acc[q*8+6], acc[q*8+7]);
        ((uint4*)dst)[q] = u;
    }
}

// ---------------------------------------------------------------------------
// Kernel 2: gather 64-ch (w1-folded) tri-plane features + softplus + scalar
// 64->33 GEMM2 with uniform (scalar-cached) w2t. No LDS, no MFMA, no syncs.
// h gathered in two 32-channel halves to cap VGPR (~100).
__global__ __launch_bounds__(256, 4) void sample_mlp(
    const unsigned short* __restrict__ planes2,
    const float* __restrict__ depths_in,   // fine pass
    const float* __restrict__ noise,       // coarse pass
    float* __restrict__ depth_out,         // coarse pass
    const float* __restrict__ origins,
    const float* __restrict__ dirs,
    const float* __restrict__ b1,
    const float* __restrict__ w2t, const float* __restrict__ b2,
    float* __restrict__ sigma_out, float* __restrict__ rgb_out,
    int coarse)
{
    int tid = threadIdx.x;
    int gid = blockIdx.x * 256 + tid;
    int ray = gid / SC;
    int b = ray >> 12;

    float depth;
    if (coarse) {
        int s = gid - ray * SC;
        depth = RAY_START + (float)s * DELTA + noise[gid] * DELTA;
        depth_out[gid] = depth;
    } else {
        depth = depths_in[gid];
    }

    float ox = origins[ray*3+0], oy = origins[ray*3+1], oz = origins[ray*3+2];
    float dx = dirs[ray*3+0],    dy = dirs[ray*3+1],    dz = dirs[ray*3+2];
    float cx = (ox + depth*dx) * 0.5f;
    float cy = (oy + depth*dy) * 0.5f;
    float cz = (oz + depth*dz) * 0.5f;

    float h[HID];
    #pragma unroll
    for (int j = 0; j < HID; ++j) h[j] = 0.f;

    #pragma unroll
    for (int half = 0; half < 2; ++half) {
        #pragma unroll
        for (int p = 0; p < 3; ++p) {
            float gx = (p == 0) ? cx : (p == 1) ? cy : cz;
            float gy = (p == 0) ? cy : (p == 1) ? cz : cx;
            float x = fmaf(gx, 128.f, 127.5f);
            float y = fmaf(gy, 128.f, 127.5f);
            float x0f = floorf(x), y0f = floorf(y);
            float wx1 = x - x0f, wy1 = y - y0f;
            int x0 = (int)x0f, y0 = (int)y0f;
            const unsigned short* pb = planes2 + ((size_t)(b*3 + p) * PLANE_HW) * HID + half * 32;
            #pragma unroll
            for (int cyi = 0; cyi < 2; ++cyi) {
                #pragma unroll
                for (int cxi = 0; cxi < 2; ++cxi) {
                    int xi = x0 + cxi, yi = y0 + cyi;
                    float wgt = ((cyi ? wy1 : 1.f - wy1) * (cxi ? wx1 : 1.f - wx1)) * (1.f/3.f);
                    if (xi < 0 || xi > 255 || yi < 0 || yi > 255) wgt = 0.f;  // OOB -> 0 (branchless)
                    int xc = min(max(xi, 0), 255), yc = min(max(yi, 0), 255);
                    const uint4* tp = (const uint4*)(pb + ((yc << 8) + xc) * HID);
                    uint4 v0 = tp[0], v1 = tp[1], v2 = tp[2], v3 = tp[3];
                    float* hh = h + half * 32;
                    fma2(v0.x, wgt, hh[0],  hh[1]);  fma2(v0.y, wgt, hh[2],  hh[3]);
                    fma2(v0.z, wgt, hh[4],  hh[5]);  fma2(v0.w, wgt, hh[6],  hh[7]);
                    fma2(v1.x, wgt, hh[8],  hh[9]);  fma2(v1.y, wgt, hh[10], hh[11]);
                    fma2(v1.z, wgt, hh[12], hh[13]); fma2(v1.w, wgt, hh[14], hh[15]);
                    fma2(v2.x, wgt, hh[16], hh[17]); fma2(v2.y, wgt, hh[18], hh[19]);
                    fma2(v2.z, wgt, hh[20], hh[21]); fma2(v2.w, wgt, hh[22], hh[23]);
                    fma2(v3.x, wgt, hh[24], hh[25]); fma2(v3.y, wgt, hh[26], hh[27]);
                    fma2(v3.z, wgt, hh[28], hh[29]); fma2(v3.w, wgt, hh[30], hh[31]);
                }
            }
        }
    }

    // softplus + b1 (b1 uniform -> scalar loads)
    #pragma unroll
    for (int j = 0; j < HID; ++j) h[j] = softplusf(h[j] + b1[j]);

    // GEMM2: o_k = b2[k] + sum_j h[j] * w2t[k*64+j]  (w2t uniform -> scalar loads)
    {
        float o0 = b2[0];
        #pragma unroll
        for (int j = 0; j < HID; ++j) o0 = fmaf(h[j], w2t[j], o0);
        sigma_out[gid] = o0;
    }
    float4* ro = (float4*)(rgb_out + (size_t)gid * 32);
    #pragma unroll
    for (int q = 0; q < 8; ++q) {
        float4 v;
        #pragma unroll
        for (int r = 0; r < 4; ++r) {
            int k = 1 + q * 4 + r;
            float ok = b2[k];
            #pragma unroll
            for (int j = 0; j < HID; ++j) ok = fmaf(h[j], w2t[k * HID + j], ok);
            ((float*)&v)[r] = 1.002f / (1.f + expf(-ok)) - 0.001f;
        }
        ro[q] = v;
    }
}

// ---------------------------------------------------------------------------
// Kernel 3: per-ray coarse ray-march -> weights -> inverse-CDF importance
__global__ __launch_bounds__(64) void importance_kernel(
    const float* __restrict__ depth_c, const float* __restrict__ sigma_c,
    const float* __restrict__ noise_imp, float* __restrict__ depth_f,
    unsigned int* __restrict__ minmax)
{
    __shared__ float s_w[64][SC-1];
    __shared__ float s_bins[64][SC-1];
    __shared__ float s_cdf[64][SC-2];
    int tid = threadIdx.x;
    int ray = blockIdx.x * 64 + tid;
    float* w    = s_w[tid];
    float* bins = s_bins[tid];
    float* cdf  = s_cdf[tid];

    const float* d  = depth_c + (size_t)ray * SC;
    const float* sg = sigma_c + (size_t)ray * SC;
    float d0 = d[0];
    float dprev = d0, sprev = sg[0];
    float T = 1.f;
    for (int i = 0; i < SC-1; ++i) {
        float d1 = d[i+1], s1 = sg[i+1];
        bins[i] = 0.5f * (dprev + d1);
        float dens = softplusf(0.5f * (sprev + s1) - 1.f);
        float a = 1.f - expf(-dens * (d1 - dprev));
        w[i] = a * T;
        T *= 1.f - a + 1e-10f;
        dprev = d1; sprev = s1;
    }
    float sum = 0.f;
    for (int i = 1; i <= 45; ++i) {
        float wn = 0.5f * (fmaxf(w[i-1], w[i]) + fmaxf(w[i], w[i+1])) + 0.01f + 1e-5f;
        cdf[i] = wn;
        sum += wn;
    }
    cdf[0] = 0.f;
    float cum = 0.f;
    for (int i = 1; i <= 45; ++i) { cum += cdf[i] / sum; cdf[i] = cum; }

    float fmn = 1e30f, fmx = -1e30f;
    const float* u_row = noise_imp + (size_t)ray * SC;
    float* df_row = depth_f + (size_t)ray * SC;
    for (int j = 0; j < SC; ++j) {
        float u = u_row[j];
        int inds = 0;
        for (int t = 0; t < 46; ++t) inds += (cdf[t] <= u) ? 1 : 0;
        int below = inds - 1; if (below < 0) below = 0;
        int above = inds;     if (above > 45) above = 45;
        float cb = cdf[below], ca = cdf[above];
        float bb = bins[below], ba = bins[above];
        float den = (ca - cb) < 1e-5f ? 1.f : (ca - cb);
        float s = bb + (u - cb) / den * (ba - bb);
        df_row[j] = s;
        fmn = fminf(fmn, s); fmx = fmaxf(fmx, s);
    }
    fmn = fminf(fmn, d0);
    fmx = fmaxf(fmx, dprev);
    atomicMin(minmax + 0, __float_as_uint(fmn));
    atomicMax(minmax + 1, __float_as_uint(fmx));
}

// ---------------------------------------------------------------------------
// Kernel 4: merge coarse+fine (stable rank sort of 96), final ray-march.
__global__ __launch_bounds__(256) void final_march(
    const float* __restrict__ depth_c, const float* __restrict__ sigma_c,
    const float* __restrict__ rgb_c,
    const float* __restrict__ depth_f, const float* __restrict__ sigma_f,
    const float* __restrict__ rgb_f,
    const unsigned int* __restrict__ minmax,
    float* __restrict__ out)
{
    __shared__ float dall[4][96];
    __shared__ float sall[4][96];
    __shared__ float dsrt[4][96];
    __shared__ float ssrt[4][96];
    __shared__ int   perm[4][96];
    __shared__ float al[4][96];

    int wid = threadIdx.x >> 6, lane = threadIdx.x & 63;
    int ray = blockIdx.x * 4 + wid;

    for (int j = lane; j < 96; j += 64) {
        float dv, sv;
        if (j < 48) { dv = depth_c[(size_t)ray*48 + j]; sv = sigma_c[(size_t)ray*48 + j]; }
        else        { dv = depth_f[(size_t)ray*48 + j-48]; sv = sigma_f[(size_t)ray*48 + j-48]; }
        dall[wid][j] = dv; sall[wid][j] = sv;
    }
    __syncthreads();
    for (int j = lane; j < 96; j += 64) {
        float dj = dall[wid][j];
        int rank = 0;
        for (int k = 0; k < 96; ++k) {
            float dk = dall[wid][k];
            rank += (dk < dj || (dk == dj && k < j)) ? 1 : 0;
        }
        dsrt[wid][rank] = dj;
        ssrt[wid][rank] = sall[wid][j];
        perm[wid][rank] = j;
    }
    __syncthreads();
    for (int i = lane; i < 95; i += 64) {
        float dlt = dsrt[wid][i+1] - dsrt[wid][i];
        float dens = softplusf(0.5f * (ssrt[wid][i] + ssrt[wid][i+1]) - 1.f);
        al[wid][i] = 1.f - expf(-dens * dlt);
    }
    __syncthreads();
    if (lane == 0) {
        float T = 1.f, wsum = 0.f, dsum = 0.f;
        for (int i = 0; i < 95; ++i) {
            float a = al[wid][i];
            float wloc = a * T;
            T *= 1.f - a + 1e-10f;
            al[wid][i] = wloc;
            wsum += wloc;
            dsum += wloc * 0.5f * (dsrt[wid][i] + dsrt[wid][i+1]);
        }
        float depth = dsum / wsum;
        if (isnan(depth)) depth = INFINITY;
        float gmn = __uint_as_float(minmax[0]);
        float gmx = __uint_as_float(minmax[1]);
        depth = fminf(fmaxf(depth, gmn), gmx);
        out[262144 + ray] = depth;
        out[270336 + ray] = wsum;
        out[278528 + ray] = T;
    }
    __syncthreads();
    int k = lane & 31, half = lane >> 5;
    int i0 = half * 48, i1 = half ? 95 : 48;
    const float* rc = rgb_c + (size_t)ray * 48 * 32;
    const float* rf = rgb_f + (size_t)ray * 48 * 32;
    float acc = 0.f;
    int j0 = perm[wid][i0];
    float cur = (j0 < 48) ? rc[j0*32 + k] : rf[(j0-48)*32 + k];
    for (int i = i0; i < i1; ++i) {
        int jn = perm[wid][i+1];
        float nxt = (jn < 48) ? rc[jn*32 + k] : rf[(jn-48)*32 + k];
        acc += al[wid][i] * (cur + nxt);
        cur = nxt;
    }
    acc *= 0.5f;
    acc += __shfl_xor(acc, 32);
    if (half == 0) out[(size_t)ray * 32 + k] = acc * 2.f - 1.f;
}

// ---------------------------------------------------------------------------
extern "C" void kernel_launch(void* const* d_in, const int* in_sizes, int n_in,
                              void* d_out, int out_size, void* d_ws, size_t ws_size,
                              hipStream_t stream) {
    const float* planes      = (const float*)d_in[0];
    const float* origins     = (const float*)d_in[1];
    const float* dirs        = (const float*)d_in[2];
    const float* w1          = (const float*)d_in[3];
    const float* b1          = (const float*)d_in[4];
    const float* w2          = (const float*)d_in[5];
    const float* b2          = (const float*)d_in[6];
    const float* noise_strat = (const float*)d_in[7];
    const float* noise_imp   = (const float*)d_in[8];
    float* out = (float*)d_out;
    float* ws  = (float*)d_ws;

    unsigned short* planes2 = (unsigned short*)(ws + OFF_PLANES2);
    float* depth_c = ws + OFF_DEPTH_C;
    float* sigma_c = ws + OFF_SIGMA_C;
    float* rgb_c   = ws + OFF_RGB_C;
    float* depth_f = ws + OFF_DEPTH_F;
    float* sigma_f = ws + OFF_SIGMA_F;
    float* rgb_f   = ws + OFF_RGB_F;
    unsigned int* minmax = (unsigned int*)(ws + OFF_MINMAX);
    float* w2t = ws + OFF_W2T;

    precompute<<<1536, 256, 0, stream>>>(planes, w1, w2, planes2, w2t, minmax);
    sample_mlp<<<NSAMP/256, 256, 0, stream>>>(planes2, nullptr, noise_strat, depth_c,
                                              origins, dirs, b1, w2t, b2,
                                              sigma_c, rgb_c, 1);
    importance_kernel<<<NRAY/64, 64, 0, stream>>>(depth_c, sigma_c, noise_imp,
                                                  depth_f, minmax);
    sample_mlp<<<NSAMP/256, 256, 0, stream>>>(planes2, depth_f, nullptr, nullptr,
                                              origins, dirs, b1, w2t, b2,
                                              sigma_f, rgb_f, 0);
    final_march<<<NRAY/4, 256, 0, stream>>>(depth_c, sigma_c, rgb_c,
                                            depth_f, sigma_f, rgb_f, minmax, out);
}